// Round 2
// baseline (5554.526 us; speedup 1.0000x reference)
//
#include <hip/hip_runtime.h>
#include <hip/hip_bf16.h>

// RNN: T=512, B=256, D_IN=256, D_LAT=512, D_OUT=256
// d_out = [outputs (T*B*256 f32) | hidden_states (T*B*512 f32)]
// Strategy:
//   1) pre-GEMM:  A = X @ Wx + bh  -> written into hidden region (in-place scratch)
//   2) scan:      h_t = relu(A_t + h_{t-1} @ Wr), 64 blocks = 16 row-groups x 4 col-blocks,
//                 Wr held in REGISTERS (128 VGPR/lane), flag-based sync among 4 col-blocks
//   3) post-GEMM: Out = H @ Wo + bo

#define TT 512
#define BB 256
#define DIN 256
#define DLAT 512
#define DOUT 256

typedef short bf16x8 __attribute__((ext_vector_type(8)));
typedef float f32x4 __attribute__((ext_vector_type(4)));

__device__ __forceinline__ unsigned short f2bf(float f) {
  union { float f; unsigned u; } v; v.f = f;
  unsigned r = v.u + (((v.u >> 16) & 1u) + 0x7fffu);  // RNE
  return (unsigned short)(r >> 16);
}
__device__ __forceinline__ unsigned pack2(float a, float b) {
  return (unsigned)f2bf(a) | ((unsigned)f2bf(b) << 16);
}

// ---------------- weight prep: f32 -> bf16, transposed [col][k], XOR-swizzled ----------------
// layout (per 128-col slice): ushort idx = (c*K + k) ^ ((c&7)<<3)   (XOR = byte bits 4-6)
__global__ __launch_bounds__(256) void prep_kernel(
    const float* __restrict__ Wh, const float* __restrict__ Wo,
    unsigned short* __restrict__ wx, unsigned short* __restrict__ wr,
    unsigned short* __restrict__ wo) {
  int id = blockIdx.x * 256 + threadIdx.x;  // 0..262143
  {  // Wr: [512][512] from Wh rows 256..767
    int k = id >> 9, col = id & 511;
    int s = col >> 7, c = col & 127;
    wr[(s << 16) + (((c << 9) | k) ^ ((c & 7) << 3))] = f2bf(Wh[(256 + k) * 512 + col]);
  }
  if (id < 131072) {  // Wx: [256][512] from Wh rows 0..255
    int k = id >> 9, col = id & 511;
    int s = col >> 7, c = col & 127;
    wx[(s << 15) + (((c << 8) | k) ^ ((c & 7) << 3))] = f2bf(Wh[id]);
  }
  if (id < 131072) {  // Wo: [512][256]
    int k = id >> 8, col = id & 255;
    int s = col >> 7, c = col & 127;
    wo[(s << 16) + (((c << 9) | k) ^ ((c & 7) << 3))] = f2bf(Wo[id]);
  }
}

// ---------------- generic GEMM + bias: C[M][NSTR] (128-col slice s) = X[M][K] @ W + bias ----
// 256 thr = 4 waves (2x2), each wave 64x64 = 4x4 mfma 16x16x32 frags. W panel whole in LDS.
template <int K, int NSTR, int SLBITS>
__global__ __launch_bounds__(256) void gemm_bias(
    const float* __restrict__ Xg, const unsigned short* __restrict__ Wp,
    const float* __restrict__ bias, float* __restrict__ Cg) {
  __shared__ unsigned short ldsW[128 * K];   // pre-swizzled panel
  __shared__ unsigned short ldsA[128 * 64];  // A tile [128 rows][64 k], XOR-swizzled
  const int tid = threadIdx.x;
  const int s = blockIdx.x & ((1 << SLBITS) - 1);     // slice inner -> X panel L2/L3 reuse
  const size_t r0 = (size_t)(blockIdx.x >> SLBITS) * 128;
  {
    const uint4* src = (const uint4*)(Wp + (size_t)s * 128 * K);
    uint4* dst = (uint4*)ldsW;
#pragma unroll
    for (int i = 0; i < (128 * K / 8) / 256; ++i) dst[tid + 256 * i] = src[tid + 256 * i];
  }
  const int lane = tid & 63, wid = tid >> 6;
  const int wm = wid >> 1, wn = wid & 1;
  const int cl = lane & 15, kh = lane >> 4;
  f32x4 acc[4][4];
#pragma unroll
  for (int nf = 0; nf < 4; ++nf) {
    float bv = bias[s * 128 + wn * 64 + nf * 16 + cl];
#pragma unroll
    for (int mf = 0; mf < 4; ++mf) { f32x4 t = {bv, bv, bv, bv}; acc[mf][nf] = t; }
  }
  __syncthreads();
  for (int k0 = 0; k0 < K; k0 += 64) {
#pragma unroll
    for (int i = 0; i < 8; ++i) {  // stage A: 128x64 f32 -> bf16 LDS
      int g = tid + 256 * i;
      int row = g >> 4, kg = g & 15;
      const float4 v = *(const float4*)&Xg[(r0 + row) * K + (k0 + kg * 4)];
      int idx = (row * 64 + kg * 4) ^ ((row & 7) << 3);
      uint2 u; u.x = pack2(v.x, v.y); u.y = pack2(v.z, v.w);
      *(uint2*)&ldsA[idx] = u;
    }
    __syncthreads();
#pragma unroll
    for (int kk = 0; kk < 2; ++kk) {
      bf16x8 aF[4], bF[4];
#pragma unroll
      for (int mf = 0; mf < 4; ++mf) {
        int row = wm * 64 + mf * 16 + cl;
        int kl = kk * 32 + 8 * kh;
        aF[mf] = *(const bf16x8*)&ldsA[(row * 64 + kl) ^ ((row & 7) << 3)];
      }
#pragma unroll
      for (int nf = 0; nf < 4; ++nf) {
        int cc = wn * 64 + nf * 16 + cl;
        int k = k0 + kk * 32 + 8 * kh;
        bF[nf] = *(const bf16x8*)&ldsW[(cc * K + k) ^ ((cc & 7) << 3)];
      }
#pragma unroll
      for (int mf = 0; mf < 4; ++mf)
#pragma unroll
        for (int nf = 0; nf < 4; ++nf)
          acc[mf][nf] = __builtin_amdgcn_mfma_f32_16x16x32_bf16(aF[mf], bF[nf], acc[mf][nf], 0, 0, 0);
    }
    __syncthreads();
  }
#pragma unroll
  for (int mf = 0; mf < 4; ++mf)
#pragma unroll
    for (int nf = 0; nf < 4; ++nf)
#pragma unroll
      for (int j = 0; j < 4; ++j)
        Cg[(r0 + wm * 64 + mf * 16 + kh * 4 + j) * NSTR + s * 128 + wn * 64 + nf * 16 + cl] =
            acc[mf][nf][j];
}

// ---------------- recurrent scan ----------------
// 64 blocks: group g = bIdx&15 (16 rows each), col-block c = bIdx>>4 (128 cols each).
// Group mates {g, g+16, g+32, g+48} are all == g (mod 8) -> same XCD under round-robin
// placement, so flag exchange stays in the shared per-XCD L2 (perf heuristic only).
// Wr slice lives in registers (2 n-frags x 16 k-iters = 128 VGPR/lane).
// Per step: A_t loads (own tile, no dep) || spin on group flags; stage h_{t-1} -> LDS bf16;
// 32 MFMAs; relu; store h_t (this IS hidden_states output + the exchange buffer); fence; flag.
__global__ __launch_bounds__(256) void scan_kernel(
    const float* __restrict__ h0, const unsigned short* __restrict__ WrP,
    float* __restrict__ Hid, int* __restrict__ flags) {
  __shared__ unsigned short ldsH[16 * 512];  // h_{t-1} tile, bf16, XOR-swizzled
  const int tid = threadIdx.x, lane = tid & 63, wid = tid >> 6;
  const int g = blockIdx.x & 15, c = blockIdx.x >> 4;  // group mates {g,g+16,g+32,g+48}
  const int r0 = g * 16;
  const int c0 = c * 128;
  const int cl = lane & 15, kh = lane >> 4;
  const int wc = c0 + wid * 32;
  int* myflags = flags + g * 4;

  // Load this wave's Wr columns into registers (one-time, from pre-swizzled global)
  bf16x8 bw0[16], bw1[16];
  {
    const unsigned short* base = WrP + (size_t)c * 65536;
    const int cb0 = wid * 32 + cl, cb1 = cb0 + 16;
#pragma unroll
    for (int kk = 0; kk < 16; ++kk) {
      int k = kk * 32 + 8 * kh;
      bw0[kk] = *(const bf16x8*)(base + (((cb0 << 9) | k) ^ ((cb0 & 7) << 3)));
      bw1[kk] = *(const bf16x8*)(base + (((cb1 << 9) | k) ^ ((cb1 & 7) << 3)));
    }
  }

  for (int t = 0; t < TT; ++t) {
    // A_t acc-init loads: own tile only (written by pre-GEMM; only we overwrite it later)
    float ai0[4], ai1[4];
    const float* At = Hid + (size_t)t * (BB * DLAT);
#pragma unroll
    for (int j = 0; j < 4; ++j) {
      ai0[j] = At[(r0 + kh * 4 + j) * DLAT + wc + cl];
      ai1[j] = At[(r0 + kh * 4 + j) * DLAT + wc + 16 + cl];
    }
    // wait for all 4 col-blocks of this group to have finished step t-1
    if (tid < 4) {
      while (__hip_atomic_load(&myflags[tid], __ATOMIC_ACQUIRE, __HIP_MEMORY_SCOPE_AGENT) < t) {}
    }
    __syncthreads();
    // stage h_{t-1}[r0:r0+16, 0:512] -> bf16 LDS
    const float* hsrc = (t == 0) ? (h0 + (size_t)r0 * DLAT)
                                 : (Hid + (size_t)(t - 1) * (BB * DLAT) + (size_t)r0 * DLAT);
#pragma unroll
    for (int i = 0; i < 8; ++i) {
      int gi = tid + 256 * i;
      int row = gi >> 7, kg = gi & 127;
      float4 v = *(const float4*)&hsrc[row * DLAT + kg * 4];
      int idx = (row * 512 + kg * 4) ^ ((row & 7) << 3);
      uint2 u; u.x = pack2(v.x, v.y); u.y = pack2(v.z, v.w);
      *(uint2*)&ldsH[idx] = u;
    }
    __syncthreads();
    f32x4 acc0 = {ai0[0], ai0[1], ai0[2], ai0[3]};
    f32x4 acc1 = {ai1[0], ai1[1], ai1[2], ai1[3]};
#pragma unroll
    for (int kk = 0; kk < 16; ++kk) {
      int k = kk * 32 + 8 * kh;
      bf16x8 aF = *(const bf16x8*)&ldsH[(cl * 512 + k) ^ ((cl & 7) << 3)];
      acc0 = __builtin_amdgcn_mfma_f32_16x16x32_bf16(aF, bw0[kk], acc0, 0, 0, 0);
      acc1 = __builtin_amdgcn_mfma_f32_16x16x32_bf16(aF, bw1[kk], acc1, 0, 0, 0);
    }
    // relu + store h_t (in-place over A_t; also the inter-block exchange buffer)
    float* Ht = Hid + (size_t)t * (BB * DLAT);
#pragma unroll
    for (int j = 0; j < 4; ++j) {
      Ht[(r0 + kh * 4 + j) * DLAT + wc + cl] = fmaxf(acc0[j], 0.f);
      Ht[(r0 + kh * 4 + j) * DLAT + wc + 16 + cl] = fmaxf(acc1[j], 0.f);
    }
    __threadfence();     // agent-scope: make our stores visible across XCDs
    __syncthreads();     // all threads' stores drained (vmcnt(0) before s_barrier)
    if (tid == 0)
      __hip_atomic_store(&myflags[c], t + 1, __ATOMIC_RELEASE, __HIP_MEMORY_SCOPE_AGENT);
  }
}

extern "C" void kernel_launch(void* const* d_in, const int* in_sizes, int n_in,
                              void* d_out, int out_size, void* d_ws, size_t ws_size,
                              hipStream_t stream) {
  const float* x  = (const float*)d_in[0];   // [T][B][256]
  const float* h0 = (const float*)d_in[1];   // [B][512]
  const float* Wh = (const float*)d_in[2];   // [768][512]
  const float* bh = (const float*)d_in[3];   // [512]
  const float* Wo = (const float*)d_in[4];   // [512][256]
  const float* bo = (const float*)d_in[5];   // [256]
  float* Out = (float*)d_out;                          // [T][B][256]
  float* Hid = Out + (size_t)TT * BB * DOUT;           // [T][B][512]

  unsigned short* ws_wx = (unsigned short*)d_ws;       // 131072 ushorts
  unsigned short* ws_wr = ws_wx + 131072;              // 262144
  unsigned short* ws_wo = ws_wr + 262144;              // 131072
  int* flags = (int*)(ws_wo + 131072);                 // 64 ints

  hipMemsetAsync(flags, 0, 64 * sizeof(int), stream);
  prep_kernel<<<1024, 256, 0, stream>>>(Wh, Wo, ws_wx, ws_wr, ws_wo);
  // A = X @ Wx + bh  (into hidden region). slice-inner grid for X reuse.
  gemm_bias<256, 512, 2><<<4096, 256, 0, stream>>>(x, ws_wx, bh, Hid);
  // sequential scan
  scan_kernel<<<64, 256, 0, stream>>>(h0, ws_wr, Hid, flags);
  // Out = H @ Wo + bo
  gemm_bias<512, 256, 1><<<2048, 256, 0, stream>>>(Hid, ws_wo, bo, Out);
}

// Round 3
// 2478.519 us; speedup vs baseline: 2.2411x; 2.2411x over previous
//
#include <hip/hip_runtime.h>
#include <hip/hip_bf16.h>

// RNN: T=512, B=256, D_IN=256, D_LAT=512, D_OUT=256
// d_out = [outputs (T*B*256 f32) | hidden_states (T*B*512 f32)]
//   1) pre-GEMM:  A = X @ Wx + bh  -> hidden region (in-place scratch)
//   2) scan:      h_t = relu(A_t + h_{t-1} @ Wr); 64 blocks = 16 groups x 4 col-blocks.
//      Wr in registers. Inter-block exchange via bf16 fragment-layout buffer using
//      sc0 sc1 (L3-coherent, cache-maintenance-free) loads/stores + relaxed flags.
//   3) post-GEMM: Out = H @ Wo + bo

#define TT 512
#define BB 256
#define DIN 256
#define DLAT 512
#define DOUT 256

typedef short bf16x8 __attribute__((ext_vector_type(8)));
typedef int   i32x4  __attribute__((ext_vector_type(4)));
typedef float f32x4  __attribute__((ext_vector_type(4)));

__device__ __forceinline__ unsigned short f2bf(float f) {
  union { float f; unsigned u; } v; v.f = f;
  unsigned r = v.u + (((v.u >> 16) & 1u) + 0x7fffu);  // RNE
  return (unsigned short)(r >> 16);
}
__device__ __forceinline__ unsigned pack2(float a, float b) {
  return (unsigned)f2bf(a) | ((unsigned)f2bf(b) << 16);
}

// ---- raw L3-coherent (sc0 sc1) memory ops: bypass L1+L2, coherence point = L3 ----
__device__ __forceinline__ i32x4 load_b128_sc(const void* p) {
  i32x4 r;
  asm volatile("global_load_dwordx4 %0, %1, off sc0 sc1" : "=v"(r) : "v"(p) : "memory");
  return r;
}
__device__ __forceinline__ void store_short_sc(void* p, unsigned v) {
  asm volatile("global_store_short %0, %1, off sc0 sc1" :: "v"(p), "v"(v) : "memory");
}
__device__ __forceinline__ void store_flag_sc(void* p, int v) {
  asm volatile("global_store_dword %0, %1, off sc0 sc1" :: "v"(p), "v"(v) : "memory");
}
__device__ __forceinline__ int load_flag_sc(const void* p) {
  int r;
  asm volatile("global_load_dword %0, %1, off sc0 sc1\n\ts_waitcnt vmcnt(0)"
               : "=v"(r) : "v"(p) : "memory");
  return r;
}
__device__ __forceinline__ void waitvm0() {
  asm volatile("s_waitcnt vmcnt(0)" ::: "memory");
  __builtin_amdgcn_sched_barrier(0);
}
__device__ __forceinline__ void waitvm8() {
  asm volatile("s_waitcnt vmcnt(8)" ::: "memory");
  __builtin_amdgcn_sched_barrier(0);
}

// ---------------- weight prep: f32 -> bf16, transposed [col][k], XOR-swizzled ----------------
__global__ __launch_bounds__(256) void prep_kernel(
    const float* __restrict__ Wh, const float* __restrict__ Wo,
    unsigned short* __restrict__ wx, unsigned short* __restrict__ wr,
    unsigned short* __restrict__ wo) {
  int id = blockIdx.x * 256 + threadIdx.x;  // 0..262143
  {  // Wr: [512][512] from Wh rows 256..767
    int k = id >> 9, col = id & 511;
    int s = col >> 7, c = col & 127;
    wr[(s << 16) + (((c << 9) | k) ^ ((c & 7) << 3))] = f2bf(Wh[(256 + k) * 512 + col]);
  }
  if (id < 131072) {  // Wx: [256][512] from Wh rows 0..255
    int k = id >> 9, col = id & 511;
    int s = col >> 7, c = col & 127;
    wx[(s << 15) + (((c << 8) | k) ^ ((c & 7) << 3))] = f2bf(Wh[id]);
  }
  if (id < 131072) {  // Wo: [512][256]
    int k = id >> 8, col = id & 255;
    int s = col >> 7, c = col & 127;
    wo[(s << 16) + (((c << 9) | k) ^ ((c & 7) << 3))] = f2bf(Wo[id]);
  }
}

// ---------------- generic GEMM + bias (unchanged from R2) ----------------
template <int K, int NSTR, int SLBITS>
__global__ __launch_bounds__(256) void gemm_bias(
    const float* __restrict__ Xg, const unsigned short* __restrict__ Wp,
    const float* __restrict__ bias, float* __restrict__ Cg) {
  __shared__ unsigned short ldsW[128 * K];
  __shared__ unsigned short ldsA[128 * 64];
  const int tid = threadIdx.x;
  const int s = blockIdx.x & ((1 << SLBITS) - 1);
  const size_t r0 = (size_t)(blockIdx.x >> SLBITS) * 128;
  {
    const uint4* src = (const uint4*)(Wp + (size_t)s * 128 * K);
    uint4* dst = (uint4*)ldsW;
#pragma unroll
    for (int i = 0; i < (128 * K / 8) / 256; ++i) dst[tid + 256 * i] = src[tid + 256 * i];
  }
  const int lane = tid & 63, wid = tid >> 6;
  const int wm = wid >> 1, wn = wid & 1;
  const int cl = lane & 15, kh = lane >> 4;
  f32x4 acc[4][4];
#pragma unroll
  for (int nf = 0; nf < 4; ++nf) {
    float bv = bias[s * 128 + wn * 64 + nf * 16 + cl];
#pragma unroll
    for (int mf = 0; mf < 4; ++mf) { f32x4 t = {bv, bv, bv, bv}; acc[mf][nf] = t; }
  }
  __syncthreads();
  for (int k0 = 0; k0 < K; k0 += 64) {
#pragma unroll
    for (int i = 0; i < 8; ++i) {
      int g = tid + 256 * i;
      int row = g >> 4, kg = g & 15;
      const float4 v = *(const float4*)&Xg[(r0 + row) * K + (k0 + kg * 4)];
      int idx = (row * 64 + kg * 4) ^ ((row & 7) << 3);
      uint2 u; u.x = pack2(v.x, v.y); u.y = pack2(v.z, v.w);
      *(uint2*)&ldsA[idx] = u;
    }
    __syncthreads();
#pragma unroll
    for (int kk = 0; kk < 2; ++kk) {
      bf16x8 aF[4], bF[4];
#pragma unroll
      for (int mf = 0; mf < 4; ++mf) {
        int row = wm * 64 + mf * 16 + cl;
        int kl = kk * 32 + 8 * kh;
        aF[mf] = *(const bf16x8*)&ldsA[(row * 64 + kl) ^ ((row & 7) << 3)];
      }
#pragma unroll
      for (int nf = 0; nf < 4; ++nf) {
        int cc = wn * 64 + nf * 16 + cl;
        int k = k0 + kk * 32 + 8 * kh;
        bF[nf] = *(const bf16x8*)&ldsW[(cc * K + k) ^ ((cc & 7) << 3)];
      }
#pragma unroll
      for (int mf = 0; mf < 4; ++mf)
#pragma unroll
        for (int nf = 0; nf < 4; ++nf)
          acc[mf][nf] = __builtin_amdgcn_mfma_f32_16x16x32_bf16(aF[mf], bF[nf], acc[mf][nf], 0, 0, 0);
    }
    __syncthreads();
  }
#pragma unroll
  for (int mf = 0; mf < 4; ++mf)
#pragma unroll
    for (int nf = 0; nf < 4; ++nf)
#pragma unroll
      for (int j = 0; j < 4; ++j)
        Cg[(r0 + wm * 64 + mf * 16 + kh * 4 + j) * NSTR + s * 128 + wn * 64 + nf * 16 + cl] =
            acc[mf][nf][j];
}

// ---------------- recurrent scan ----------------
// 64 blocks: group g = bIdx&15 (16 rows), col-block c = bIdx>>4 (128 cols).
// h exchanged via bf16 fragment-layout buffer ex[buf2][16 groups][16 rows][512 cols],
// double-buffered (write buf t&1, read buf (t+1)&1). All exchange traffic sc0 sc1
// (L3-coherent) -> NO buffer_wbl2 / buffer_inv anywhere. Flags: relaxed sc1, init -1;
// flag[c]=t+1 after step t; step t waits all flags>=t (lockstep => 2-buffer safe).
__global__ __launch_bounds__(256) void scan_kernel(
    const float* __restrict__ h0, const unsigned short* __restrict__ WrP,
    float* __restrict__ Hid, int* __restrict__ flags, unsigned short* __restrict__ ex) {
  const int tid = threadIdx.x, lane = tid & 63, wid = tid >> 6;
  const int g = blockIdx.x & 15, c = blockIdx.x >> 4;
  const int r0 = g * 16;
  const int c0 = c * 128;
  const int cl = lane & 15, kh = lane >> 4;
  const int wc = c0 + wid * 32;
  int* flags4 = flags + g * 4;

  // One-time: Wr slice -> registers (plain cached loads; written by prep kernel)
  bf16x8 bw0[16], bw1[16];
  {
    const unsigned short* base = WrP + (size_t)c * 65536;
    const int cb0 = wid * 32 + cl, cb1 = cb0 + 16;
#pragma unroll
    for (int kk = 0; kk < 16; ++kk) {
      int k = kk * 32 + 8 * kh;
      bw0[kk] = *(const bf16x8*)(base + (((cb0 << 9) | k) ^ ((cb0 & 7) << 3)));
      bw1[kk] = *(const bf16x8*)(base + (((cb1 << 9) | k) ^ ((cb1 & 7) << 3)));
    }
  }

  // Prologue: publish own slice of h0 (bf16) into buf 1, then flag = 0
  {
    int row = tid >> 4;          // 0..15
    int cb = (tid & 15) * 8;     // 0..120
    unsigned short* exW = ex + (16 + g) * 8192 + row * 512 + c0 + cb;
    const float* hs = h0 + (size_t)(r0 + row) * DLAT + c0 + cb;
#pragma unroll
    for (int q = 0; q < 8; ++q) store_short_sc(exW + q, f2bf(hs[q]));
    waitvm0();
  }
  __syncthreads();
  if (tid == 0) store_flag_sc(&flags4[c], 0);

  for (int t = 0; t < TT; ++t) {
    // A_t init loads (own tile, plain cached) — issued before the poll to hide latency
    float ai0[4], ai1[4];
    const float* At = Hid + (size_t)t * (BB * DLAT);
#pragma unroll
    for (int j = 0; j < 4; ++j) {
      ai0[j] = At[(r0 + kh * 4 + j) * DLAT + wc + cl];
      ai1[j] = At[(r0 + kh * 4 + j) * DLAT + wc + 16 + cl];
    }
    // wait: all 4 col-blocks of this group finished step t-1 (raw sc1 polls, no inv)
    if (tid < 4) {
      while (load_flag_sc(&flags4[tid]) < t) {}
    }
    __syncthreads();

    // h_{t-1} A-fragments: direct global->VGPR sc1 loads from exchange buf
    const unsigned short* exR = ex + (((t + 1) & 1) * 16 + g) * 8192;
    i32x4 fa[16];
#pragma unroll
    for (int kk = 0; kk < 16; ++kk)
      fa[kk] = load_b128_sc(exR + cl * 512 + kk * 32 + kh * 8);

    f32x4 acc0 = {ai0[0], ai0[1], ai0[2], ai0[3]};
    f32x4 acc1 = {ai1[0], ai1[1], ai1[2], ai1[3]};
    waitvm8();  // first 8 loads complete (vmem returns in order)
#pragma unroll
    for (int kk = 0; kk < 8; ++kk) {
      bf16x8 aF = __builtin_bit_cast(bf16x8, fa[kk]);
      acc0 = __builtin_amdgcn_mfma_f32_16x16x32_bf16(aF, bw0[kk], acc0, 0, 0, 0);
      acc1 = __builtin_amdgcn_mfma_f32_16x16x32_bf16(aF, bw1[kk], acc1, 0, 0, 0);
    }
    waitvm0();
#pragma unroll
    for (int kk = 8; kk < 16; ++kk) {
      bf16x8 aF = __builtin_bit_cast(bf16x8, fa[kk]);
      acc0 = __builtin_amdgcn_mfma_f32_16x16x32_bf16(aF, bw0[kk], acc0, 0, 0, 0);
      acc1 = __builtin_amdgcn_mfma_f32_16x16x32_bf16(aF, bw1[kk], acc1, 0, 0, 0);
    }

    // relu; store h_t: f32 -> Hid (plain, output only), bf16 -> exchange (sc1)
    float* Ht = Hid + (size_t)t * (BB * DLAT);
    unsigned short* exW = ex + ((t & 1) * 16 + g) * 8192;
    float v0[4], v1[4];
#pragma unroll
    for (int j = 0; j < 4; ++j) {
      v0[j] = fmaxf(acc0[j], 0.f);
      v1[j] = fmaxf(acc1[j], 0.f);
      Ht[(r0 + kh * 4 + j) * DLAT + wc + cl] = v0[j];
      Ht[(r0 + kh * 4 + j) * DLAT + wc + 16 + cl] = v1[j];
    }
    if (t < TT - 1) {
#pragma unroll
      for (int j = 0; j < 4; ++j) {
        store_short_sc(exW + (kh * 4 + j) * 512 + wc + cl, f2bf(v0[j]));
        store_short_sc(exW + (kh * 4 + j) * 512 + wc + 16 + cl, f2bf(v1[j]));
      }
      waitvm0();        // own stores reached L3 (sc1 ack)
      __syncthreads();  // all 256 threads' stores drained
      if (tid == 0) store_flag_sc(&flags4[c], t + 1);
    }
  }
}

extern "C" void kernel_launch(void* const* d_in, const int* in_sizes, int n_in,
                              void* d_out, int out_size, void* d_ws, size_t ws_size,
                              hipStream_t stream) {
  const float* x  = (const float*)d_in[0];   // [T][B][256]
  const float* h0 = (const float*)d_in[1];   // [B][512]
  const float* Wh = (const float*)d_in[2];   // [768][512]
  const float* bh = (const float*)d_in[3];   // [512]
  const float* Wo = (const float*)d_in[4];   // [512][256]
  const float* bo = (const float*)d_in[5];   // [256]
  float* Out = (float*)d_out;                          // [T][B][256]
  float* Hid = Out + (size_t)TT * BB * DOUT;           // [T][B][512]

  unsigned short* ws_wx = (unsigned short*)d_ws;       // 131072 ushorts
  unsigned short* ws_wr = ws_wx + 131072;              // 262144
  unsigned short* ws_wo = ws_wr + 262144;              // 131072
  int* flags = (int*)(ws_wo + 131072);                 // 64 ints
  unsigned short* ex = (unsigned short*)(flags + 64);  // 2*16*8192 ushorts (512 KB)

  hipMemsetAsync(flags, 0xFF, 64 * sizeof(int), stream);  // flags = -1
  prep_kernel<<<1024, 256, 0, stream>>>(Wh, Wo, ws_wx, ws_wr, ws_wo);
  gemm_bias<256, 512, 2><<<4096, 256, 0, stream>>>(x, ws_wx, bh, Hid);
  scan_kernel<<<64, 256, 0, stream>>>(h0, ws_wr, Hid, flags, ex);
  gemm_bias<512, 256, 1><<<2048, 256, 0, stream>>>(Hid, ws_wo, bo, Out);
}

// Round 5
// 2284.622 us; speedup vs baseline: 2.4313x; 1.0849x over previous
//
#include <hip/hip_runtime.h>
#include <hip/hip_bf16.h>

// RNN: T=512, B=256, D_IN=256, D_LAT=512, D_OUT=256
// d_out = [outputs (T*B*256 f32) | hidden_states (T*B*512 f32)]
//   1) pre-GEMM:  A = X @ Wx + bh  -> hidden region (in-place scratch)
//   2) scan:      h_t = relu(A_t + h_{t-1} @ Wr); 64 blocks = 16 groups x 4 col-blocks.
//      Wr in registers (rotated so own k-slice is first -> static indexing).
//      Exchange: LDS-transposed, fully-coalesced dwordx4 sc0sc1 stores; own k-slice
//      fragments read from LDS; foreign from L3 with split vmcnt overlap.
//   3) post-GEMM: Out = H @ Wo + bo

#define TT 512
#define BB 256
#define DIN 256
#define DLAT 512
#define DOUT 256

typedef short bf16x8 __attribute__((ext_vector_type(8)));
typedef int   i32x4  __attribute__((ext_vector_type(4)));
typedef float f32x4  __attribute__((ext_vector_type(4)));

__device__ __forceinline__ unsigned short f2bf(float f) {
  union { float f; unsigned u; } v; v.f = f;
  unsigned r = v.u + (((v.u >> 16) & 1u) + 0x7fffu);  // RNE
  return (unsigned short)(r >> 16);
}
__device__ __forceinline__ unsigned pack2(float a, float b) {
  return (unsigned)f2bf(a) | ((unsigned)f2bf(b) << 16);
}

// ---- raw L3-coherent (sc0 sc1) ops: bypass L1+L2, coherence point = L3 ----
__device__ __forceinline__ i32x4 load_b128_sc(const void* p) {
  i32x4 r;
  asm volatile("global_load_dwordx4 %0, %1, off sc0 sc1" : "=v"(r) : "v"(p) : "memory");
  return r;
}
__device__ __forceinline__ void store_b128_sc(void* p, i32x4 v) {
  asm volatile("global_store_dwordx4 %0, %1, off sc0 sc1" :: "v"(p), "v"(v) : "memory");
}
__device__ __forceinline__ void store_flag_sc(void* p, int v) {
  asm volatile("global_store_dword %0, %1, off sc0 sc1" :: "v"(p), "v"(v) : "memory");
}
__device__ __forceinline__ int load_flag_sc(const void* p) {
  int r;
  asm volatile("global_load_dword %0, %1, off sc0 sc1\n\ts_waitcnt vmcnt(0)"
               : "=v"(r) : "v"(p) : "memory");
  return r;
}
__device__ __forceinline__ void waitvm0() {
  asm volatile("s_waitcnt vmcnt(0)" ::: "memory");
  __builtin_amdgcn_sched_barrier(0);
}
__device__ __forceinline__ void waitvm6() {
  asm volatile("s_waitcnt vmcnt(6)" ::: "memory");
  __builtin_amdgcn_sched_barrier(0);
}

// ---------------- weight prep: f32 -> bf16, transposed [col][k], XOR-swizzled ----------------
__global__ __launch_bounds__(256) void prep_kernel(
    const float* __restrict__ Wh, const float* __restrict__ Wo,
    unsigned short* __restrict__ wx, unsigned short* __restrict__ wr,
    unsigned short* __restrict__ wo) {
  int id = blockIdx.x * 256 + threadIdx.x;  // 0..262143
  {  // Wr: [512][512] from Wh rows 256..767
    int k = id >> 9, col = id & 511;
    int s = col >> 7, c = col & 127;
    wr[(s << 16) + (((c << 9) | k) ^ ((c & 7) << 3))] = f2bf(Wh[(256 + k) * 512 + col]);
  }
  if (id < 131072) {  // Wx: [256][512] from Wh rows 0..255
    int k = id >> 9, col = id & 511;
    int s = col >> 7, c = col & 127;
    wx[(s << 15) + (((c << 8) | k) ^ ((c & 7) << 3))] = f2bf(Wh[id]);
  }
  if (id < 131072) {  // Wo: [512][256]
    int k = id >> 8, col = id & 255;
    int s = col >> 7, c = col & 127;
    wo[(s << 16) + (((c << 9) | k) ^ ((c & 7) << 3))] = f2bf(Wo[id]);
  }
}

// ---------------- generic GEMM + bias (unchanged) ----------------
template <int K, int NSTR, int SLBITS>
__global__ __launch_bounds__(256) void gemm_bias(
    const float* __restrict__ Xg, const unsigned short* __restrict__ Wp,
    const float* __restrict__ bias, float* __restrict__ Cg) {
  __shared__ unsigned short ldsW[128 * K];
  __shared__ unsigned short ldsA[128 * 64];
  const int tid = threadIdx.x;
  const int s = blockIdx.x & ((1 << SLBITS) - 1);
  const size_t r0 = (size_t)(blockIdx.x >> SLBITS) * 128;
  {
    const uint4* src = (const uint4*)(Wp + (size_t)s * 128 * K);
    uint4* dst = (uint4*)ldsW;
#pragma unroll
    for (int i = 0; i < (128 * K / 8) / 256; ++i) dst[tid + 256 * i] = src[tid + 256 * i];
  }
  const int lane = tid & 63, wid = tid >> 6;
  const int wm = wid >> 1, wn = wid & 1;
  const int cl = lane & 15, kh = lane >> 4;
  f32x4 acc[4][4];
#pragma unroll
  for (int nf = 0; nf < 4; ++nf) {
    float bv = bias[s * 128 + wn * 64 + nf * 16 + cl];
#pragma unroll
    for (int mf = 0; mf < 4; ++mf) { f32x4 t = {bv, bv, bv, bv}; acc[mf][nf] = t; }
  }
  __syncthreads();
  for (int k0 = 0; k0 < K; k0 += 64) {
#pragma unroll
    for (int i = 0; i < 8; ++i) {
      int g = tid + 256 * i;
      int row = g >> 4, kg = g & 15;
      const float4 v = *(const float4*)&Xg[(r0 + row) * K + (k0 + kg * 4)];
      int idx = (row * 64 + kg * 4) ^ ((row & 7) << 3);
      uint2 u; u.x = pack2(v.x, v.y); u.y = pack2(v.z, v.w);
      *(uint2*)&ldsA[idx] = u;
    }
    __syncthreads();
#pragma unroll
    for (int kk = 0; kk < 2; ++kk) {
      bf16x8 aF[4], bF[4];
#pragma unroll
      for (int mf = 0; mf < 4; ++mf) {
        int row = wm * 64 + mf * 16 + cl;
        int kl = kk * 32 + 8 * kh;
        aF[mf] = *(const bf16x8*)&ldsA[(row * 64 + kl) ^ ((row & 7) << 3)];
      }
#pragma unroll
      for (int nf = 0; nf < 4; ++nf) {
        int cc = wn * 64 + nf * 16 + cl;
        int k = k0 + kk * 32 + 8 * kh;
        bF[nf] = *(const bf16x8*)&ldsW[(cc * K + k) ^ ((cc & 7) << 3)];
      }
#pragma unroll
      for (int mf = 0; mf < 4; ++mf)
#pragma unroll
        for (int nf = 0; nf < 4; ++nf)
          acc[mf][nf] = __builtin_amdgcn_mfma_f32_16x16x32_bf16(aF[mf], bF[nf], acc[mf][nf], 0, 0, 0);
    }
    __syncthreads();
  }
#pragma unroll
  for (int mf = 0; mf < 4; ++mf)
#pragma unroll
    for (int nf = 0; nf < 4; ++nf)
#pragma unroll
      for (int j = 0; j < 4; ++j)
        Cg[(r0 + wm * 64 + mf * 16 + kh * 4 + j) * NSTR + s * 128 + wn * 64 + nf * 16 + cl] =
            acc[mf][nf][j];
}

// ---------------- recurrent scan ----------------
// 64 blocks: group g = bIdx&15 (16 rows), col-block c = bIdx>>4 (128 cols).
// ex[buf2][16 groups][16 rows][512 cols] bf16 in fragment-friendly row-major layout.
// Per step: [ai loads | own-frag LDS reads | poll flags] barrier
//   [acc init; issue 12 foreign b128 sc0sc1; MFMA own(LDS); vmcnt(6); 6; vmcnt(0); 6]
//   [relu; LDS transpose] barrier [1x dwordx4 sc0sc1 store; vmcnt(0)] barrier [flag]
//   [Hid f32 stores -- off critical path]
__global__ __launch_bounds__(256) void scan_kernel(
    const float* __restrict__ h0, const unsigned short* __restrict__ WrP,
    float* __restrict__ Hid, int* __restrict__ flags, unsigned short* __restrict__ ex) {
  __shared__ unsigned short lt[16][136];  // our 16x128 slice, +8 pad
  const int tid = threadIdx.x, lane = tid & 63, wid = tid >> 6;
  const int g = blockIdx.x & 15, c = blockIdx.x >> 4;
  const int r0 = g * 16;
  const int c0 = c * 128;
  const int cl = lane & 15, kh = lane >> 4;
  const int wc = c0 + wid * 32;
  int* flags4 = flags + g * 4;

  // Wr slice -> registers, ROTATED: bwR[i] holds k-block kk=(4c+i)&15, so own
  // k-slices are i=0..3 and all register indices below are compile-time.
  bf16x8 bwR0[16], bwR1[16];
  {
    const unsigned short* base = WrP + (size_t)c * 65536;
    const int cb0 = wid * 32 + cl, cb1 = cb0 + 16;
#pragma unroll
    for (int i = 0; i < 16; ++i) {
      int kk = (c * 4 + i) & 15;
      int k = kk * 32 + 8 * kh;
      bwR0[i] = *(const bf16x8*)(base + (((cb0 << 9) | k) ^ ((cb0 & 7) << 3)));
      bwR1[i] = *(const bf16x8*)(base + (((cb1 << 9) | k) ^ ((cb1 & 7) << 3)));
    }
  }

  // Prologue: publish own h0 slice (bf16) to buf1 (coalesced) + local copy in lt
  {
    int r = tid >> 4, cb = (tid & 15) * 8;
    const float* hs = h0 + (size_t)(r0 + r) * DLAT + c0 + cb;
    float4 a = *(const float4*)&hs[0];
    float4 b = *(const float4*)&hs[4];
    i32x4 w;
    w[0] = (int)pack2(a.x, a.y); w[1] = (int)pack2(a.z, a.w);
    w[2] = (int)pack2(b.x, b.y); w[3] = (int)pack2(b.z, b.w);
    *(i32x4*)&lt[r][cb] = w;
    store_b128_sc(ex + (size_t)(16 + g) * 8192 + r * 512 + c0 + cb, w);
    waitvm0();
  }
  __syncthreads();
  if (tid == 0) store_flag_sc(&flags4[c], 0);

  for (int t = 0; t < TT; ++t) {
    // A_t init loads (own tile, plain cached; hidden under the poll)
    float ai0[4], ai1[4];
    const float* At = Hid + (size_t)t * (BB * DLAT);
#pragma unroll
    for (int j = 0; j < 4; ++j) {
      ai0[j] = At[(r0 + kh * 4 + j) * DLAT + wc + cl];
      ai1[j] = At[(r0 + kh * 4 + j) * DLAT + wc + 16 + cl];
    }
    // own k-slice A-fragments from LDS (h_{t-1} slice we computed ourselves)
    i32x4 of[4];
#pragma unroll
    for (int i = 0; i < 4; ++i) of[i] = *(const i32x4*)&lt[cl][i * 32 + kh * 8];
    // wait: all 4 col-blocks of this group finished step t-1
    if (tid < 4) {
      while (load_flag_sc(&flags4[tid]) < t) {}
    }
    __syncthreads();  // barrier 1: drains of[] reads; gates lt overwrite below

    f32x4 acc0 = {ai0[0], ai0[1], ai0[2], ai0[3]};
    f32x4 acc1 = {ai1[0], ai1[1], ai1[2], ai1[3]};
    __builtin_amdgcn_sched_barrier(0);

    // issue 12 foreign fragment loads (rotated order i=4..15)
    const unsigned short* exR = ex + (size_t)(((t + 1) & 1) * 16 + g) * 8192;
    i32x4 fa[12];
#pragma unroll
    for (int i = 0; i < 12; ++i) {
      int kk = (c * 4 + 4 + i) & 15;
      fa[i] = load_b128_sc(exR + cl * 512 + kk * 32 + kh * 8);
    }
    // own 4 k-slices from LDS while foreign loads fly
#pragma unroll
    for (int i = 0; i < 4; ++i) {
      bf16x8 aF = __builtin_bit_cast(bf16x8, of[i]);
      acc0 = __builtin_amdgcn_mfma_f32_16x16x32_bf16(aF, bwR0[i], acc0, 0, 0, 0);
      acc1 = __builtin_amdgcn_mfma_f32_16x16x32_bf16(aF, bwR1[i], acc1, 0, 0, 0);
    }
    waitvm6();
#pragma unroll
    for (int i = 0; i < 6; ++i) {
      bf16x8 aF = __builtin_bit_cast(bf16x8, fa[i]);
      acc0 = __builtin_amdgcn_mfma_f32_16x16x32_bf16(aF, bwR0[4 + i], acc0, 0, 0, 0);
      acc1 = __builtin_amdgcn_mfma_f32_16x16x32_bf16(aF, bwR1[4 + i], acc1, 0, 0, 0);
    }
    waitvm0();
#pragma unroll
    for (int i = 6; i < 12; ++i) {
      bf16x8 aF = __builtin_bit_cast(bf16x8, fa[i]);
      acc0 = __builtin_amdgcn_mfma_f32_16x16x32_bf16(aF, bwR0[4 + i], acc0, 0, 0, 0);
      acc1 = __builtin_amdgcn_mfma_f32_16x16x32_bf16(aF, bwR1[4 + i], acc1, 0, 0, 0);
    }

    // relu; transpose to LDS (bf16)
    float v0[4], v1[4];
#pragma unroll
    for (int j = 0; j < 4; ++j) {
      v0[j] = fmaxf(acc0[j], 0.f);
      v1[j] = fmaxf(acc1[j], 0.f);
      lt[kh * 4 + j][wid * 32 + cl] = f2bf(v0[j]);
      lt[kh * 4 + j][wid * 32 + 16 + cl] = f2bf(v1[j]);
    }
    if (t < TT - 1) {
      __syncthreads();  // barrier 2: transpose visible
      int r = tid >> 4, cb = (tid & 15) * 8;
      i32x4 w = *(const i32x4*)&lt[r][cb];
      store_b128_sc(ex + (size_t)((t & 1) * 16 + g) * 8192 + r * 512 + c0 + cb, w);
      waitvm0();        // own store acked at L3
      __syncthreads();  // barrier 3: all threads' stores acked
      if (tid == 0) store_flag_sc(&flags4[c], t + 1);
    }
    // Hid f32 output stores — after flag, off the critical path
    float* Ht = Hid + (size_t)t * (BB * DLAT);
#pragma unroll
    for (int j = 0; j < 4; ++j) {
      Ht[(r0 + kh * 4 + j) * DLAT + wc + cl] = v0[j];
      Ht[(r0 + kh * 4 + j) * DLAT + wc + 16 + cl] = v1[j];
    }
  }
}

extern "C" void kernel_launch(void* const* d_in, const int* in_sizes, int n_in,
                              void* d_out, int out_size, void* d_ws, size_t ws_size,
                              hipStream_t stream) {
  const float* x  = (const float*)d_in[0];   // [T][B][256]
  const float* h0 = (const float*)d_in[1];   // [B][512]
  const float* Wh = (const float*)d_in[2];   // [768][512]
  const float* bh = (const float*)d_in[3];   // [512]
  const float* Wo = (const float*)d_in[4];   // [512][256]
  const float* bo = (const float*)d_in[5];   // [256]
  float* Out = (float*)d_out;                          // [T][B][256]
  float* Hid = Out + (size_t)TT * BB * DOUT;           // [T][B][512]

  unsigned short* ws_wx = (unsigned short*)d_ws;       // 131072 ushorts
  unsigned short* ws_wr = ws_wx + 131072;              // 262144
  unsigned short* ws_wo = ws_wr + 262144;              // 131072
  int* flags = (int*)(ws_wo + 131072);                 // 64 ints
  unsigned short* ex = (unsigned short*)(flags + 64);  // 2*16*8192 ushorts (512 KB)

  hipMemsetAsync(flags, 0xFF, 64 * sizeof(int), stream);  // flags = -1
  prep_kernel<<<1024, 256, 0, stream>>>(Wh, Wo, ws_wx, ws_wr, ws_wo);
  gemm_bias<256, 512, 2><<<4096, 256, 0, stream>>>(x, ws_wx, bh, Hid);
  scan_kernel<<<64, 256, 0, stream>>>(h0, ws_wr, Hid, flags, ex);
  gemm_bias<512, 256, 1><<<2048, 256, 0, stream>>>(Hid, ws_wo, bo, Out);
}